// Round 4
// baseline (611.143 us; speedup 1.0000x reference)
//
#include <hip/hip_runtime.h>
#include <hip/hip_bf16.h>
#include <math.h>

#define T_TOK   8192
#define D_MODEL 1024
#define DFFN    2048
#define N_EXP   8
#define NASSIGN (T_TOK*2)

#define TM 256          // GEMM tile M
#define BN 256          // GEMM tile N
#define BK 64
#define TILE_MAX 72

// ---- workspace layout (byte offsets) ----
#define WS_ZSUM     0        // float
#define WS_PSUM     4        // 8 floats
#define WS_COUNTS   64       // 8 ints
#define WS_CURSOR   96       // 8 ints
#define WS_OFFS     128      // 8 ints
#define WS_NTILES   160      // int
#define WS_QHEAD    164      // int
#define WS_QTOTAL   168      // int
#define WS_DONE1    256      // TILE_MAX ints (gemm1 n-blocks done per tile)
#define WS_TMAP     1024     // TILE_MAX*4 ints (e, gr, valid, pad)
#define WS_QITEMS   2560     // up to TILE_MAX*12 ints
#define WS_SEL      8192     // NASSIGN ints
#define WS_WGT      73728    // NASSIGN floats
#define WS_AIDX     139264   // NASSIGN ints
#define WS_AW       204800   // NASSIGN floats
#define WS_XB       270336                    // T_TOK*D_MODEL bf16   (16 MB)
#define WS_W1T      (WS_XB + 16777216)        // [e][n][k] bf16       (32 MB)
#define WS_W2T      (WS_W1T + 33554432)       // [e][n][k] bf16       (32 MB)
#define WS_H        (WS_W2T + 33554432)       // NASSIGN*DFFN bf16    (64 MB)
// total ≈ 151.3 MB

typedef __attribute__((ext_vector_type(8))) short bf16x8;
typedef __attribute__((ext_vector_type(4))) float f32x4;
typedef __attribute__((ext_vector_type(4))) unsigned int u32x4;

static __device__ __forceinline__ unsigned short f2bf(float f) {
    unsigned int u = __builtin_bit_cast(unsigned int, f);
    u += 0x7fffu + ((u >> 16) & 1u);
    return (unsigned short)(u >> 16);
}

// async global->LDS, 16B per lane; LDS side must be wave-base + lane*16.
static __device__ __forceinline__ void gll16(const unsigned short* g, unsigned short* l) {
    __builtin_amdgcn_global_load_lds(
        (const __attribute__((address_space(1))) unsigned int*)g,
        (__attribute__((address_space(3))) unsigned int*)l, 16, 0, 0);
}

// LDS element offset of fragment chunk (row, kc) under the XOR swizzle.
static __device__ __forceinline__ int frag_off(int row, int kc) {
    return (row * 8 + (kc ^ (row & 7))) * 8;
}

// in: [E][K][N] fp32 -> out: [E][N][K] bf16 (64x64 tiles)
__global__ __launch_bounds__(256) void transpose_cvt_kernel(
    const float* __restrict__ in, unsigned short* __restrict__ out, int K, int N)
{
    int e = blockIdx.z;
    const float* inp = in + (size_t)e * K * N;
    unsigned short* outp = out + (size_t)e * K * N;
    __shared__ unsigned short tile[64][68];
    int k0 = blockIdx.y * 64, n0 = blockIdx.x * 64;
    int tid = threadIdx.x;
    int r = tid >> 4, c4 = (tid & 15) * 4;
    #pragma unroll
    for (int p = 0; p < 4; ++p) {
        int k = r + p * 16;
        float4 v = *(const float4*)(inp + (size_t)(k0 + k) * N + n0 + c4);
        tile[k][c4+0] = f2bf(v.x);
        tile[k][c4+1] = f2bf(v.y);
        tile[k][c4+2] = f2bf(v.z);
        tile[k][c4+3] = f2bf(v.w);
    }
    __syncthreads();
    int n = tid >> 2, kc = (tid & 3) * 16;
    unsigned short t[16];
    #pragma unroll
    for (int j = 0; j < 16; ++j) t[j] = tile[kc + j][n];
    unsigned short* o = outp + (size_t)(n0 + n) * K + k0 + kc;
    *(u32x4*)o       = *(u32x4*)t;
    *(u32x4*)(o + 8) = *(u32x4*)(t + 8);
}

// ---------------- router (fused x -> bf16 conversion) ----------------
__global__ __launch_bounds__(256) void router_kernel(
    const float* __restrict__ x, const float* __restrict__ rw,
    float* zsum, float* psum, int* counts, int* sel, float* wgt,
    unsigned short* __restrict__ xb)
{
    __shared__ float xs[32*129];
    __shared__ float rs[8*129];
    __shared__ float lg[32*9];
    __shared__ float blk_p[8];
    __shared__ int   blk_c[8];
    __shared__ float blk_z;
    int tid = threadIdx.x;
    if (tid < 8) { blk_p[tid] = 0.f; blk_c[tid] = 0; }
    if (tid == 8) blk_z = 0.f;
    int tb = blockIdx.x * 32;
    int tt = tid >> 3, e = tid & 7;
    float acc = 0.f;
    for (int c = 0; c < 8; ++c) {
        int c0 = c * 128;
        #pragma unroll
        for (int p = 0; p < 16; ++p) {
            int flat = p * 256 + tid;
            int r = flat >> 7, col = flat & 127;
            xs[r*129 + col] = x[(size_t)(tb + r)*D_MODEL + c0 + col];
        }
        #pragma unroll
        for (int p = 0; p < 4; ++p) {
            int flat = p * 256 + tid;
            int er = flat >> 7, col = flat & 127;
            rs[er*129 + col] = rw[(size_t)er*D_MODEL + c0 + col];
        }
        __syncthreads();
        {
            int rr = tid >> 3, cc = (tid & 7) * 16;
            unsigned short tmp[16];
            #pragma unroll
            for (int j = 0; j < 16; ++j) tmp[j] = f2bf(xs[rr*129 + cc + j]);
            unsigned short* o = xb + (size_t)(tb + rr)*D_MODEL + c0 + cc;
            *(u32x4*)o       = *(u32x4*)tmp;
            *(u32x4*)(o + 8) = *(u32x4*)(tmp + 8);
        }
        #pragma unroll 8
        for (int i = 0; i < 128; ++i)
            acc += xs[tt*129 + i] * rs[e*129 + i];
        __syncthreads();
    }
    lg[tt*9 + e] = acc;
    __syncthreads();
    if (tid < 32) {
        int t = tb + tid;
        float l[8], p[8];
        float mx = -1e30f;
        #pragma unroll
        for (int j = 0; j < 8; ++j) { l[j] = lg[tid*9 + j]; mx = fmaxf(mx, l[j]); }
        float se = 0.f;
        #pragma unroll
        for (int j = 0; j < 8; ++j) { p[j] = expf(l[j] - mx); se += p[j]; }
        float inv = 1.f / se;
        #pragma unroll
        for (int j = 0; j < 8; ++j) p[j] *= inv;
        float lse = mx + logf(se);
        atomicAdd(&blk_z, lse*lse);
        #pragma unroll
        for (int j = 0; j < 8; ++j) atomicAdd(&blk_p[j], p[j]);
        int i0 = 0; float b0 = p[0];
        #pragma unroll
        for (int j = 1; j < 8; ++j) if (p[j] > b0) { b0 = p[j]; i0 = j; }
        int i1 = -1; float b1 = -1.f;
        #pragma unroll
        for (int j = 0; j < 8; ++j) if (j != i0 && p[j] > b1) { b1 = p[j]; i1 = j; }
        float s = b0 + b1;
        sel[t*2+0] = i0; sel[t*2+1] = i1;
        wgt[t*2+0] = b0 / s; wgt[t*2+1] = b1 / s;
        atomicAdd(&blk_c[i0], 1); atomicAdd(&blk_c[i1], 1);
    }
    __syncthreads();
    if (tid < 8) {
        atomicAdd(&counts[tid], blk_c[tid]);
        unsafeAtomicAdd(&psum[tid], blk_p[tid]);
    }
    if (tid == 8) unsafeAtomicAdd(zsum, blk_z);
}

// ---------------- offsets + tile map + work queue + aux-loss ----------------
__global__ void finalize_kernel(const int* counts, const float* psum, const float* zsum,
                                int* offs, int* ntiles, int* tmap, int* qitems,
                                int* qtotal, float* out_tail)
{
    if (threadIdx.x != 0) return;
    int off = 0, nt = 0;
    float lb = 0.f;
    for (int e = 0; e < N_EXP; ++e) {
        int c = counts[e];
        offs[e] = off;
        for (int m0 = 0; m0 < c; m0 += TM) {
            tmap[nt*4+0] = e;
            tmap[nt*4+1] = off + m0;
            tmap[nt*4+2] = min(TM, c - m0);
            tmap[nt*4+3] = 0;
            nt++;
        }
        float fi = (float)c / (float)NASSIGN;
        out_tail[2 + e] = fi;
        lb += fi * (psum[e] / (float)T_TOK);
        off += c;
    }
    *ntiles = nt;
    // work queue: all gemm1 items first (tile-major), then gemm2 items.
    // item = type<<14 | tile<<4 | nblk
    int q = 0;
    for (int t = 0; t < nt; ++t)
        for (int nb = 0; nb < DFFN/BN; ++nb)
            qitems[q++] = (0 << 14) | (t << 4) | nb;
    for (int t = 0; t < nt; ++t)
        for (int nb = 0; nb < D_MODEL/BN; ++nb)
            qitems[q++] = (1 << 14) | (t << 4) | nb;
    *qtotal = q;
    out_tail[0] = zsum[0] / (float)T_TOK;
    out_tail[1] = (float)N_EXP * lb;
}

// ---------------- scatter tokens into per-expert segments ----------------
__global__ __launch_bounds__(256) void scatter_kernel(
    const int* __restrict__ sel, const float* __restrict__ wgt,
    const int* __restrict__ offs, int* cursor, int* aidx, float* aw)
{
    int t = blockIdx.x * 256 + threadIdx.x;
    if (t >= T_TOK) return;
    #pragma unroll
    for (int k = 0; k < 2; ++k) {
        int e = sel[t*2 + k];
        int pos = atomicAdd(&cursor[e], 1);
        int r = offs[e] + pos;
        aidx[r] = t;
        aw[r] = wgt[t*2 + k];
    }
}

// ---------------- GEMM tile bodies (shared K-loop discipline) ----------------
// 256x256 tile, 512 threads (8 waves 2Mx4N), double-buffered LDS,
// cross-barrier prefetch with counted vmcnt.

static __device__ __forceinline__ void gemm1_tile(
    int e, int gr, int valid, int n0,
    const unsigned short* __restrict__ xb, const unsigned short* __restrict__ w1t,
    const int* __restrict__ aidx, unsigned short* __restrict__ H,
    unsigned short (*As)[TM*BK], unsigned short (*Bs)[TM*BK], int tid)
{
    int lane = tid & 63, wave = tid >> 6;
    int wm = (wave >> 2) * 128, wn = (wave & 3) * 64;
    int q = lane >> 4, r16 = lane & 15;
    f32x4 acc[8][4];
    #pragma unroll
    for (int i = 0; i < 8; ++i)
        #pragma unroll
        for (int j = 0; j < 4; ++j) acc[i][j] = (f32x4){0.f, 0.f, 0.f, 0.f};

    const unsigned short* aga[4];
    const unsigned short* bga[4];
    int coff[4];
    #pragma unroll
    for (int u = 0; u < 4; ++u) {
        int cc = tid + u*512;
        int m = cc >> 3, kl = cc & 7;
        int kg = kl ^ (m & 7);
        int tok = aidx[gr + min(m, valid - 1)];
        aga[u] = xb + (size_t)tok * D_MODEL + kg*8;
        bga[u] = w1t + ((size_t)(e * DFFN + n0 + m)) * D_MODEL + kg*8;
        coff[u] = cc * 8;
    }

    const int NK = D_MODEL / BK;   // 16
    #pragma unroll
    for (int u = 0; u < 4; ++u) gll16(aga[u], &As[0][coff[u]]);
    #pragma unroll
    for (int u = 0; u < 4; ++u) gll16(bga[u], &Bs[0][coff[u]]);

    int cur = 0;
    for (int kt = 0; kt < NK; ++kt) {
        if (kt + 1 < NK) {
            int ko = (kt + 1) * BK;
            #pragma unroll
            for (int u = 0; u < 4; ++u) gll16(aga[u] + ko, &As[cur^1][coff[u]]);
            #pragma unroll
            for (int u = 0; u < 4; ++u) gll16(bga[u] + ko, &Bs[cur^1][coff[u]]);
            asm volatile("s_waitcnt vmcnt(8)" ::: "memory");
        } else {
            asm volatile("s_waitcnt vmcnt(0)" ::: "memory");
        }
        __builtin_amdgcn_sched_barrier(0);
        __builtin_amdgcn_s_barrier();
        asm volatile("" ::: "memory");
        const unsigned short* Ab = &As[cur][0];
        const unsigned short* Bb = &Bs[cur][0];
        __builtin_amdgcn_s_setprio(1);
        #pragma unroll
        for (int kh = 0; kh < 2; ++kh) {
            bf16x8 af[8], bfr[4];
            #pragma unroll
            for (int im = 0; im < 8; ++im)
                af[im] = *(const bf16x8*)&Ab[frag_off(wm + im*16 + r16, q + 4*kh)];
            #pragma unroll
            for (int in = 0; in < 4; ++in)
                bfr[in] = *(const bf16x8*)&Bb[frag_off(wn + in*16 + r16, q + 4*kh)];
            #pragma unroll
            for (int im = 0; im < 8; ++im)
                #pragma unroll
                for (int in = 0; in < 4; ++in)
                    acc[im][in] = __builtin_amdgcn_mfma_f32_16x16x32_bf16(af[im], bfr[in], acc[im][in], 0, 0, 0);
        }
        __builtin_amdgcn_s_setprio(0);
        asm volatile("" ::: "memory");
        __builtin_amdgcn_sched_barrier(0);
        __builtin_amdgcn_s_barrier();
        cur ^= 1;
    }
    #pragma unroll
    for (int im = 0; im < 8; ++im) {
        #pragma unroll
        for (int reg = 0; reg < 4; ++reg) {
            int m = wm + im*16 + q*4 + reg;
            if (m < valid) {
                size_t rowbase = (size_t)(gr + m) * DFFN + n0 + wn;
                #pragma unroll
                for (int in = 0; in < 4; ++in) {
                    float v = acc[im][in][reg];
                    float g = 0.5f * v * (1.0f + erff(v * 0.70710678118654752f));
                    H[rowbase + in*16 + r16] = f2bf(g);
                }
            }
        }
    }
}

static __device__ __forceinline__ void gemm2_tile(
    int e, int gr, int valid, int n0,
    const unsigned short* __restrict__ H, const unsigned short* __restrict__ w2t,
    const int* __restrict__ aidx, const float* __restrict__ aw,
    unsigned short (*As)[TM*BK], unsigned short (*Bs)[TM*BK],
    float* __restrict__ out, int tid)
{
    int lane = tid & 63, wave = tid >> 6;
    int wm = (wave >> 2) * 128, wn = (wave & 3) * 64;
    int q = lane >> 4, r16 = lane & 15;
    f32x4 acc[8][4];
    #pragma unroll
    for (int i = 0; i < 8; ++i)
        #pragma unroll
        for (int j = 0; j < 4; ++j) acc[i][j] = (f32x4){0.f, 0.f, 0.f, 0.f};

    const unsigned short* aga[4];
    const unsigned short* bga[4];
    int coff[4];
    #pragma unroll
    for (int u = 0; u < 4; ++u) {
        int cc = tid + u*512;
        int m = cc >> 3, kl = cc & 7;
        int kg = kl ^ (m & 7);
        aga[u] = H + (size_t)(gr + min(m, valid - 1)) * DFFN + kg*8;
        bga[u] = w2t + (size_t)e * (DFFN * D_MODEL) + (size_t)(n0 + m) * DFFN + kg*8;
        coff[u] = cc * 8;
    }

    const int NK = DFFN / BK;   // 32
    #pragma unroll
    for (int u = 0; u < 4; ++u) gll16(aga[u], &As[0][coff[u]]);
    #pragma unroll
    for (int u = 0; u < 4; ++u) gll16(bga[u], &Bs[0][coff[u]]);

    int cur = 0;
    for (int kt = 0; kt < NK; ++kt) {
        if (kt + 1 < NK) {
            int ko = (kt + 1) * BK;
            #pragma unroll
            for (int u = 0; u < 4; ++u) gll16(aga[u] + ko, &As[cur^1][coff[u]]);
            #pragma unroll
            for (int u = 0; u < 4; ++u) gll16(bga[u] + ko, &Bs[cur^1][coff[u]]);
            asm volatile("s_waitcnt vmcnt(8)" ::: "memory");
        } else {
            asm volatile("s_waitcnt vmcnt(0)" ::: "memory");
        }
        __builtin_amdgcn_sched_barrier(0);
        __builtin_amdgcn_s_barrier();
        asm volatile("" ::: "memory");
        const unsigned short* Ab = &As[cur][0];
        const unsigned short* Bb = &Bs[cur][0];
        __builtin_amdgcn_s_setprio(1);
        #pragma unroll
        for (int kh = 0; kh < 2; ++kh) {
            bf16x8 af[8], bfr[4];
            #pragma unroll
            for (int im = 0; im < 8; ++im)
                af[im] = *(const bf16x8*)&Ab[frag_off(wm + im*16 + r16, q + 4*kh)];
            #pragma unroll
            for (int in = 0; in < 4; ++in)
                bfr[in] = *(const bf16x8*)&Bb[frag_off(wn + in*16 + r16, q + 4*kh)];
            #pragma unroll
            for (int im = 0; im < 8; ++im)
                #pragma unroll
                for (int in = 0; in < 4; ++in)
                    acc[im][in] = __builtin_amdgcn_mfma_f32_16x16x32_bf16(af[im], bfr[in], acc[im][in], 0, 0, 0);
        }
        __builtin_amdgcn_s_setprio(0);
        asm volatile("" ::: "memory");
        __builtin_amdgcn_sched_barrier(0);
        __builtin_amdgcn_s_barrier();
        cur ^= 1;
    }
    #pragma unroll
    for (int im = 0; im < 8; ++im) {
        #pragma unroll
        for (int reg = 0; reg < 4; ++reg) {
            int m = wm + im*16 + q*4 + reg;
            if (m < valid) {
                int t = aidx[gr + m];
                float w = aw[gr + m];
                float* orow = out + (size_t)t*D_MODEL + n0 + wn;
                #pragma unroll
                for (int in = 0; in < 4; ++in)
                    unsafeAtomicAdd(&orow[in*16 + r16], w * acc[im][in][reg]);
            }
        }
    }
}

// ---------------- persistent merged GEMM1+GEMM2 with work queue ----------------
// Launched via hipLaunchCooperativeKernel: co-residency of all blocks is
// GUARANTEED (validated by the runtime), so the done1 spin cannot deadlock:
// any popped gemm2 item's gemm1 producers are popped (queue order) and thus
// either finished or running on a co-resident block that progresses freely.
__global__ __launch_bounds__(512, 1) void moe_gemm_kernel(
    const unsigned short* __restrict__ xb, const unsigned short* __restrict__ w1t,
    const unsigned short* __restrict__ w2t, unsigned short* __restrict__ H,
    const int* __restrict__ aidx, const float* __restrict__ aw,
    const int* __restrict__ tmap, const int* __restrict__ qitems,
    int* qhead, const int* qtotal, int* done1, float* __restrict__ out)
{
    __shared__ unsigned short As[2][TM*BK];
    __shared__ unsigned short Bs[2][TM*BK];
    __shared__ int s_item;
    int tid = threadIdx.x;
    int qt = *qtotal;
    for (;;) {
        __syncthreads();
        if (tid == 0) s_item = atomicAdd(qhead, 1);
        __syncthreads();
        int it = s_item;
        if (it >= qt) return;
        int item = qitems[it];
        int type = item >> 14;
        int tile = (item >> 4) & 1023;
        int nb   = item & 15;
        int e     = tmap[tile*4+0];
        int gr    = tmap[tile*4+1];
        int valid = tmap[tile*4+2];
        if (type == 0) {
            gemm1_tile(e, gr, valid, nb * BN, xb, w1t, aidx, H, As, Bs, tid);
            __threadfence();          // make H stores visible device-wide
            __syncthreads();          // all waves' stores+fences done
            if (tid == 0) atomicAdd(&done1[tile], 1);
        } else {
            if (tid == 0) {
                while (__hip_atomic_load(done1 + tile, __ATOMIC_ACQUIRE,
                                         __HIP_MEMORY_SCOPE_AGENT) < DFFN/BN)
                    __builtin_amdgcn_s_sleep(8);
            }
            __syncthreads();
            __threadfence();
            gemm2_tile(e, gr, valid, nb * BN, H, w2t, aidx, aw, As, Bs, out, tid);
        }
    }
}

// ---------------- fallback static kernels (no cross-block deps; R2-verified) ---
__global__ __launch_bounds__(512, 1) void gemm1_fb_kernel(
    const unsigned short* __restrict__ xb, const unsigned short* __restrict__ w1t,
    const int* __restrict__ aidx, const int* __restrict__ tmap,
    const int* __restrict__ ntiles, unsigned short* __restrict__ H)
{
    int bid = blockIdx.x;
    int xcd = bid & 7;
    int jj  = bid >> 3;
    int tile = (jj >> 3) * 8 + xcd;
    int n0   = (jj & 7) * BN;
    if (tile >= *ntiles) return;
    __shared__ unsigned short As[2][TM*BK];
    __shared__ unsigned short Bs[2][TM*BK];
    gemm1_tile(tmap[tile*4+0], tmap[tile*4+1], tmap[tile*4+2], n0,
               xb, w1t, aidx, H, As, Bs, threadIdx.x);
}

__global__ __launch_bounds__(512, 1) void gemm2_fb_kernel(
    const unsigned short* __restrict__ H, const unsigned short* __restrict__ w2t,
    const int* __restrict__ aidx, const float* __restrict__ aw,
    const int* __restrict__ tmap, const int* __restrict__ ntiles,
    float* __restrict__ out)
{
    int bid = blockIdx.x;
    int xcd = bid & 7;
    int jj  = bid >> 3;
    int tile = (jj >> 2) * 8 + xcd;
    int n0   = (jj & 3) * BN;
    if (tile >= *ntiles) return;
    __shared__ unsigned short As[2][TM*BK];
    __shared__ unsigned short Bs[2][TM*BK];
    gemm2_tile(tmap[tile*4+0], tmap[tile*4+1], tmap[tile*4+2], n0,
               H, w2t, aidx, aw, As, Bs, out, threadIdx.x);
}

extern "C" void kernel_launch(void* const* d_in, const int* in_sizes, int n_in,
                              void* d_out, int out_size, void* d_ws, size_t ws_size,
                              hipStream_t stream)
{
    const float* x  = (const float*)d_in[0];
    const float* rw = (const float*)d_in[1];
    const float* w1 = (const float*)d_in[2];
    const float* w2 = (const float*)d_in[3];
    float* out = (float*)d_out;
    char* ws = (char*)d_ws;
    float* zsum   = (float*)(ws + WS_ZSUM);
    float* psum   = (float*)(ws + WS_PSUM);
    int*   counts = (int*)(ws + WS_COUNTS);
    int*   cursor = (int*)(ws + WS_CURSOR);
    int*   offs   = (int*)(ws + WS_OFFS);
    int*   ntiles = (int*)(ws + WS_NTILES);
    int*   qhead  = (int*)(ws + WS_QHEAD);
    int*   qtotal = (int*)(ws + WS_QTOTAL);
    int*   done1  = (int*)(ws + WS_DONE1);
    int*   tmap   = (int*)(ws + WS_TMAP);
    int*   qitems = (int*)(ws + WS_QITEMS);
    int*   sel    = (int*)(ws + WS_SEL);
    float* wgt    = (float*)(ws + WS_WGT);
    int*   aidx   = (int*)(ws + WS_AIDX);
    float* aw     = (float*)(ws + WS_AW);
    unsigned short* xb  = (unsigned short*)(ws + WS_XB);
    unsigned short* w1t = (unsigned short*)(ws + WS_W1T);
    unsigned short* w2t = (unsigned short*)(ws + WS_W2T);
    unsigned short* H   = (unsigned short*)(ws + WS_H);

    hipMemsetAsync(d_out, 0, (size_t)T_TOK * D_MODEL * sizeof(float), stream);
    hipMemsetAsync(ws, 0, 2560, stream);   // scalars + counters + done1

    // W1: [K=1024][E*N=16384] -> [16384][1024]
    transpose_cvt_kernel<<<dim3(16384/64, 1024/64, 1), 256, 0, stream>>>(w1, w1t, 1024, 16384);
    // W2: per expert [K=2048][N=1024] -> [1024][2048]
    transpose_cvt_kernel<<<dim3(1024/64, 2048/64, 8), 256, 0, stream>>>(w2, w2t, 2048, 1024);

    router_kernel<<<T_TOK/32, 256, 0, stream>>>(x, rw, zsum, psum, counts, sel, wgt, xb);
    finalize_kernel<<<1, 64, 0, stream>>>(counts, psum, zsum, offs, ntiles, tmap,
                                          qitems, qtotal, out + (size_t)T_TOK * D_MODEL);
    scatter_kernel<<<T_TOK/256, 256, 0, stream>>>(sel, wgt, offs, cursor, aidx, aw);

    // cooperative grid size: validated co-residency, cached once
    static int coopGrid = -2;   // -2 = uninitialized
    if (coopGrid == -2) {
        int nb = 0;
        hipError_t oe = hipOccupancyMaxActiveBlocksPerMultiprocessor(
            &nb, moe_gemm_kernel, 512, 0);
        if (oe != hipSuccess || nb < 1) {
            coopGrid = -1;      // occupancy query failed -> use fallback path
        } else {
            hipDeviceProp_t prop;
            int cus = 256;
            if (hipGetDeviceProperties(&prop, 0) == hipSuccess)
                cus = prop.multiProcessorCount;
            int cap = nb * cus;
            coopGrid = cap < 256 ? cap : 256;
            if (coopGrid < 1) coopGrid = -1;
        }
    }

    bool launched = false;
    if (coopGrid > 0) {
        void* args[] = { (void*)&xb, (void*)&w1t, (void*)&w2t, (void*)&H,
                         (void*)&aidx, (void*)&aw, (void*)&tmap, (void*)&qitems,
                         (void*)&qhead, (void*)&qtotal, (void*)&done1, (void*)&out };
        hipError_t le = hipLaunchCooperativeKernel(
            (const void*)moe_gemm_kernel, dim3(coopGrid), dim3(512), args, 0, stream);
        if (le == hipSuccess) launched = true;
        else coopGrid = -1;   // remember failure; don't retry every call
    }
    if (!launched) {
        // spin-free fallback: two static dispatches (R2-verified structure)
        gemm1_fb_kernel<<<dim3(TILE_MAX * (DFFN/BN)), 512, 0, stream>>>(
            xb, w1t, aidx, tmap, ntiles, H);
        gemm2_fb_kernel<<<dim3(TILE_MAX * (D_MODEL/BN)), 512, 0, stream>>>(
            H, w2t, aidx, aw, tmap, ntiles, out);
    }
}